// Round 1
// baseline (116.621 us; speedup 1.0000x reference)
//
#include <hip/hip_runtime.h>
#include <math.h>

#define NN 2048
#define EE 65536
#define FF 7
#define SS 32
#define LL 16

__device__ __forceinline__ float sigmoidf_(float x) { return 1.f / (1.f + expf(-x)); }

// state[n][s] = relu(x[n] @ W_in[:,s] + b_in[s])
__global__ void enc_kernel(const float* __restrict__ x, const float* __restrict__ W_in,
                           const float* __restrict__ b_in, float* __restrict__ state) {
    int idx = blockIdx.x * blockDim.x + threadIdx.x;
    if (idx >= NN * SS) return;
    int n = idx >> 5, s = idx & 31;
    float acc = b_in[s];
    const float* xr = x + n * FF;
#pragma unroll
    for (int k = 0; k < FF; k++) acc += xr[k] * W_in[k * SS + s];
    state[idx] = fmaxf(acc, 0.f);
}

// msg[n][s] = relu(state[n] @ Wm[:,s] + bm[s])
__global__ void msg_kernel(const float* __restrict__ state, const float* __restrict__ Wm,
                           const float* __restrict__ bm, float* __restrict__ msg) {
    int idx = blockIdx.x * blockDim.x + threadIdx.x;
    if (idx >= NN * SS) return;
    int n = idx >> 5, s = idx & 31;
    float acc = bm[s];
    const float* sr = state + n * SS;
#pragma unroll
    for (int k = 0; k < SS; k++) acc += sr[k] * Wm[k * SS + s];
    msg[idx] = fmaxf(acc, 0.f);
}

// agg[dst[e]][s] += msg[src[e]][s]
__global__ void scatter_kernel(const float* __restrict__ msg, const int* __restrict__ ei,
                               float* __restrict__ agg) {
    int idx = blockIdx.x * blockDim.x + threadIdx.x;
    if (idx >= EE * SS) return;
    int e = idx >> 5, s = idx & 31;
    int src = ei[e], dst = ei[EE + e];
    atomicAdd(&agg[dst * SS + s], msg[src * SS + s]);
}

// GRUCell(agg, state) with residual; reads st_in, writes st_out (double-buffered)
__global__ void gru_kernel(const float* __restrict__ agg, const float* __restrict__ st_in,
                           const float* __restrict__ Wih, const float* __restrict__ Whh,
                           const float* __restrict__ bih, const float* __restrict__ bhh,
                           float* __restrict__ st_out) {
    int idx = blockIdx.x * blockDim.x + threadIdx.x;
    if (idx >= NN * SS) return;
    int n = idx >> 5, s = idx & 31;
    const float* ar = agg + n * SS;
    const float* hrow = st_in + n * SS;
    float xr = bih[s], xz = bih[SS + s], xn = bih[2 * SS + s];
    float hr = bhh[s], hz = bhh[SS + s], hn = bhh[2 * SS + s];
#pragma unroll
    for (int k = 0; k < SS; k++) {
        float av = ar[k], hv = hrow[k];
        const float* wi = Wih + k * 3 * SS;
        const float* wh = Whh + k * 3 * SS;
        xr += av * wi[s];
        xz += av * wi[SS + s];
        xn += av * wi[2 * SS + s];
        hr += hv * wh[s];
        hz += hv * wh[SS + s];
        hn += hv * wh[2 * SS + s];
    }
    float rg = sigmoidf_(xr + hr);
    float zg = sigmoidf_(xz + hz);
    float ng = tanhf(xn + rg * hn);
    float h0 = hrow[s];
    float nh = (1.f - zg) * ng + zg * h0;
    st_out[idx] = h0 + nh;
}

// mu/logstd heads; also stash mu in ws for decoder
__global__ void heads_kernel(const float* __restrict__ state, const float* __restrict__ W_mu,
                             const float* __restrict__ b_mu, const float* __restrict__ W_ls,
                             const float* __restrict__ b_ls, float* __restrict__ mu_ws,
                             float* __restrict__ out_mu, float* __restrict__ out_ls) {
    int idx = blockIdx.x * blockDim.x + threadIdx.x;
    if (idx >= NN * LL) return;
    int n = idx >> 4, l = idx & 15;
    const float* sr = state + n * SS;
    float m = b_mu[l], v = b_ls[l];
#pragma unroll
    for (int k = 0; k < SS; k++) {
        m += sr[k] * W_mu[k * LL + l];
        v += sr[k] * W_ls[k * LL + l];
    }
    mu_ws[idx] = m;
    out_mu[idx] = m;
    out_ls[idx] = v;
}

// a = mu @ W_d1[:L], b = mu @ W_d1[L:]
__global__ void ab_kernel(const float* __restrict__ mu, const float* __restrict__ W_d1,
                          float* __restrict__ A, float* __restrict__ B) {
    int idx = blockIdx.x * blockDim.x + threadIdx.x;
    if (idx >= NN * LL) return;
    int n = idx >> 4, l = idx & 15;
    const float* mr = mu + n * LL;
    float av = 0.f, bv = 0.f;
#pragma unroll
    for (int k = 0; k < LL; k++) {
        av += mr[k] * W_d1[k * LL + l];
        bv += mr[k] * W_d1[(LL + k) * LL + l];
    }
    A[idx] = av;
    B[idx] = bv;
}

// out[i][j] = sigmoid( 0.5*(l(i,j)+l(j,i)) + b_d2 )
// l(i,j) = sum_l W_d2[l]*relu(a_i[l]+b_j[l]+b_d1[l])
__global__ __launch_bounds__(256) void dec_kernel(const float* __restrict__ A,
                                                  const float* __restrict__ B,
                                                  const float* __restrict__ b_d1,
                                                  const float* __restrict__ W_d2,
                                                  const float* __restrict__ b_d2,
                                                  float* __restrict__ out) {
    int j = blockIdx.x * 64 + (threadIdx.x & 63);
    int i = blockIdx.y * 4 + (threadIdx.x >> 6);
    const float4* A4 = (const float4*)A;
    const float4* B4 = (const float4*)B;
    float ai[16], bj[16], aj[16], bi[16];
#pragma unroll
    for (int q = 0; q < 4; q++) {
        float4 t;
        t = A4[i * 4 + q]; ai[4 * q] = t.x; ai[4 * q + 1] = t.y; ai[4 * q + 2] = t.z; ai[4 * q + 3] = t.w;
        t = B4[j * 4 + q]; bj[4 * q] = t.x; bj[4 * q + 1] = t.y; bj[4 * q + 2] = t.z; bj[4 * q + 3] = t.w;
        t = A4[j * 4 + q]; aj[4 * q] = t.x; aj[4 * q + 1] = t.y; aj[4 * q + 2] = t.z; aj[4 * q + 3] = t.w;
        t = B4[i * 4 + q]; bi[4 * q] = t.x; bi[4 * q + 1] = t.y; bi[4 * q + 2] = t.z; bi[4 * q + 3] = t.w;
    }
    float lij = 0.f, lji = 0.f;
#pragma unroll
    for (int l = 0; l < LL; l++) {
        float w = W_d2[l];
        float c = b_d1[l];
        lij += w * fmaxf(ai[l] + bj[l] + c, 0.f);
        lji += w * fmaxf(aj[l] + bi[l] + c, 0.f);
    }
    float logit = 0.5f * (lij + lji) + b_d2[0];
    out[i * NN + j] = 1.f / (1.f + expf(-logit));
}

extern "C" void kernel_launch(void* const* d_in, const int* in_sizes, int n_in,
                              void* d_out, int out_size, void* d_ws, size_t ws_size,
                              hipStream_t stream) {
    const float* x    = (const float*)d_in[0];
    const int*   ei   = (const int*)d_in[1];
    const float* W_in = (const float*)d_in[2];
    const float* b_in = (const float*)d_in[3];
    const float* W_msg = (const float*)d_in[4];
    const float* b_msg = (const float*)d_in[5];
    const float* W_ih = (const float*)d_in[6];
    const float* W_hh = (const float*)d_in[7];
    const float* b_ih = (const float*)d_in[8];
    const float* b_hh = (const float*)d_in[9];
    const float* W_mu = (const float*)d_in[10];
    const float* b_mu = (const float*)d_in[11];
    const float* W_ls = (const float*)d_in[12];
    const float* b_ls = (const float*)d_in[13];
    const float* W_d1 = (const float*)d_in[14];
    const float* b_d1 = (const float*)d_in[15];
    const float* W_d2 = (const float*)d_in[16];
    const float* b_d2 = (const float*)d_in[17];

    float* ws = (float*)d_ws;
    float* state0 = ws;                 // N*S
    float* state1 = state0 + NN * SS;   // N*S
    float* msg    = state1 + NN * SS;   // N*S
    float* agg    = msg + NN * SS;      // N*S
    float* mu_ws  = agg + NN * SS;      // N*L
    float* A      = mu_ws + NN * LL;    // N*L
    float* B      = A + NN * LL;        // N*L

    float* out_adj = (float*)d_out;
    float* out_mu  = out_adj + NN * NN;
    float* out_ls  = out_mu + NN * LL;

    const int T = 256;
    enc_kernel<<<(NN * SS + T - 1) / T, T, 0, stream>>>(x, W_in, b_in, state0);

    float* st_cur = state0;
    float* st_nxt = state1;
    for (int r = 0; r < 3; r++) {
        msg_kernel<<<(NN * SS + T - 1) / T, T, 0, stream>>>(
            st_cur, W_msg + r * SS * SS, b_msg + r * SS, msg);
        hipMemsetAsync(agg, 0, NN * SS * sizeof(float), stream);
        scatter_kernel<<<(EE * SS + T - 1) / T, T, 0, stream>>>(msg, ei, agg);
        gru_kernel<<<(NN * SS + T - 1) / T, T, 0, stream>>>(
            agg, st_cur, W_ih + r * SS * 3 * SS, W_hh + r * SS * 3 * SS,
            b_ih + r * 3 * SS, b_hh + r * 3 * SS, st_nxt);
        float* tmp = st_cur; st_cur = st_nxt; st_nxt = tmp;
    }

    heads_kernel<<<(NN * LL + T - 1) / T, T, 0, stream>>>(
        st_cur, W_mu, b_mu, W_ls, b_ls, mu_ws, out_mu, out_ls);
    ab_kernel<<<(NN * LL + T - 1) / T, T, 0, stream>>>(mu_ws, W_d1, A, B);

    dim3 dgrid(NN / 64, NN / 4);
    dec_kernel<<<dgrid, 256, 0, stream>>>(A, B, b_d1, W_d2, b_d2, out_adj);
}

// Round 2
// 77.731 us; speedup vs baseline: 1.5003x; 1.5003x over previous
//
#include <hip/hip_runtime.h>
#include <math.h>

#define NN 2048
#define EE 65536
#define FF 7
#define SS 32
#define LL 16

__device__ __forceinline__ float sigmoidf_(float x) { return 1.f / (1.f + expf(-x)); }

// K1: state = relu(x@W_in+b_in); msg = relu(state@Wm0+bm0); zero agg0.
// Block = 256 threads = 8 rows x 32 lanes.
__global__ void enc_msg_kernel(const float* __restrict__ x,
                               const float* __restrict__ W_in, const float* __restrict__ b_in,
                               const float* __restrict__ Wm, const float* __restrict__ bm,
                               float* __restrict__ state_out, float* __restrict__ msg,
                               float* __restrict__ agg) {
    __shared__ float lds[256];
    int tid = threadIdx.x;
    int n = blockIdx.x * 8 + (tid >> 5);
    int s = tid & 31;
    const float* xr = x + n * FF;
    float acc = b_in[s];
#pragma unroll
    for (int k = 0; k < FF; k++) acc += xr[k] * W_in[k * SS + s];
    float st = fmaxf(acc, 0.f);
    state_out[n * SS + s] = st;
    lds[tid] = st;
    __syncthreads();
    const float* row = lds + (tid & ~31);
    float m = bm[s];
#pragma unroll
    for (int k = 0; k < SS; k++) m += row[k] * Wm[k * SS + s];
    msg[n * SS + s] = fmaxf(m, 0.f);
    agg[n * SS + s] = 0.f;
}

// agg[dst[e]][s] += msg[src[e]][s]
__global__ void scatter_kernel(const float* __restrict__ msg, const int* __restrict__ ei,
                               float* __restrict__ agg) {
    int idx = blockIdx.x * blockDim.x + threadIdx.x;
    int e = idx >> 5, s = idx & 31;
    int src = ei[e], dst = ei[EE + e];
    atomicAdd(&agg[dst * SS + s], msg[src * SS + s]);
}

// GRU round r (residual) + message for round r+1 + zero aggNext.
__global__ void gru_msg_kernel(const float* __restrict__ agg_in, const float* __restrict__ st_in,
                               const float* __restrict__ Wih, const float* __restrict__ Whh,
                               const float* __restrict__ bih, const float* __restrict__ bhh,
                               const float* __restrict__ Wm, const float* __restrict__ bm,
                               float* __restrict__ st_out, float* __restrict__ msg,
                               float* __restrict__ agg_next) {
    __shared__ float lds[256];
    int tid = threadIdx.x;
    int n = blockIdx.x * 8 + (tid >> 5);
    int s = tid & 31;
    const float* ar = agg_in + n * SS;
    const float* hrow = st_in + n * SS;
    float xr = bih[s], xz = bih[SS + s], xn = bih[2 * SS + s];
    float hr = bhh[s], hz = bhh[SS + s], hn = bhh[2 * SS + s];
#pragma unroll
    for (int k = 0; k < SS; k++) {
        float av = ar[k], hv = hrow[k];
        const float* wi = Wih + k * 3 * SS;
        const float* wh = Whh + k * 3 * SS;
        xr += av * wi[s];
        xz += av * wi[SS + s];
        xn += av * wi[2 * SS + s];
        hr += hv * wh[s];
        hz += hv * wh[SS + s];
        hn += hv * wh[2 * SS + s];
    }
    float rg = sigmoidf_(xr + hr);
    float zg = sigmoidf_(xz + hz);
    float ng = tanhf(xn + rg * hn);
    float h0 = hrow[s];
    float st = h0 + (1.f - zg) * ng + zg * h0;
    st_out[n * SS + s] = st;
    lds[tid] = st;
    __syncthreads();
    const float* row = lds + (tid & ~31);
    float m = bm[s];
#pragma unroll
    for (int k = 0; k < SS; k++) m += row[k] * Wm[k * SS + s];
    msg[n * SS + s] = fmaxf(m, 0.f);
    agg_next[n * SS + s] = 0.f;
}

// Final GRU round + mu/logstd heads + A' (b_d1 folded) / B decoder operands.
__global__ void gru_heads_kernel(const float* __restrict__ agg_in, const float* __restrict__ st_in,
                                 const float* __restrict__ Wih, const float* __restrict__ Whh,
                                 const float* __restrict__ bih, const float* __restrict__ bhh,
                                 const float* __restrict__ W_mu, const float* __restrict__ b_mu,
                                 const float* __restrict__ W_ls, const float* __restrict__ b_ls,
                                 const float* __restrict__ W_d1, const float* __restrict__ b_d1,
                                 float* __restrict__ out_mu, float* __restrict__ out_ls,
                                 float* __restrict__ Abuf, float* __restrict__ Bbuf) {
    __shared__ float lds_st[256];
    __shared__ float lds_mu[8 * LL];
    int tid = threadIdx.x;
    int rl = tid >> 5;
    int n = blockIdx.x * 8 + rl;
    int s = tid & 31;
    const float* ar = agg_in + n * SS;
    const float* hrow = st_in + n * SS;
    float xr = bih[s], xz = bih[SS + s], xn = bih[2 * SS + s];
    float hr = bhh[s], hz = bhh[SS + s], hn = bhh[2 * SS + s];
#pragma unroll
    for (int k = 0; k < SS; k++) {
        float av = ar[k], hv = hrow[k];
        const float* wi = Wih + k * 3 * SS;
        const float* wh = Whh + k * 3 * SS;
        xr += av * wi[s];
        xz += av * wi[SS + s];
        xn += av * wi[2 * SS + s];
        hr += hv * wh[s];
        hz += hv * wh[SS + s];
        hn += hv * wh[2 * SS + s];
    }
    float rg = sigmoidf_(xr + hr);
    float zg = sigmoidf_(xz + hz);
    float ng = tanhf(xn + rg * hn);
    float h0 = hrow[s];
    float st = h0 + (1.f - zg) * ng + zg * h0;
    lds_st[tid] = st;
    __syncthreads();
    const float* row = lds_st + rl * SS;
    int l = s & 15;
    {   // heads: lanes 0-15 -> mu, lanes 16-31 -> logstd
        const float* W = (s < 16) ? W_mu : W_ls;
        float v = (s < 16) ? b_mu[l] : b_ls[l];
#pragma unroll
        for (int k = 0; k < SS; k++) v += row[k] * W[k * LL + l];
        if (s < 16) { out_mu[n * LL + l] = v; lds_mu[rl * LL + l] = v; }
        else out_ls[n * LL + l] = v;
    }
    __syncthreads();
    {   // A' = mu@W_d1[:L] + b_d1 ; B = mu@W_d1[L:]
        const float* murow = lds_mu + rl * LL;
        const float* Wd = W_d1 + ((s < 16) ? 0 : LL * LL);
        float v = (s < 16) ? b_d1[l] : 0.f;
#pragma unroll
        for (int k = 0; k < LL; k++) v += murow[k] * Wd[k * LL + l];
        if (s < 16) Abuf[n * LL + l] = v;
        else Bbuf[n * LL + l] = v;
    }
}

// Triangular-tiled decoder: block handles 64x64 (bi,bj) tile with bi<=bj,
// computes symmetric prob once per unordered pair, writes tile + transpose.
__global__ __launch_bounds__(256) void dec_kernel(const float* __restrict__ Abuf,
                                                  const float* __restrict__ Bbuf,
                                                  const float* __restrict__ W_d2,
                                                  const float* __restrict__ b_d2,
                                                  float* __restrict__ out) {
    __shared__ float ldsAj[LL * 64];
    __shared__ float ldsBj[LL * 64];
    __shared__ float ldsT[64 * 65];
    int t = blockIdx.x;
    // decode triangular index: offset(bi) = (65*bi - bi*bi)/2
    int bi = (int)((65.f - sqrtf(4225.f - 8.f * (float)t)) * 0.5f);
    if (bi < 0) bi = 0;
    if (bi > 31) bi = 31;
    while (bi > 0 && (65 * bi - bi * bi) / 2 > t) bi--;
    while (bi < 31 && (65 * (bi + 1) - (bi + 1) * (bi + 1)) / 2 <= t) bi++;
    int bj = bi + (t - (65 * bi - bi * bi) / 2);
    int i0 = bi * 64, j0 = bj * 64;
    int tid = threadIdx.x;

    {   // stage j-side rows transposed into LDS (coalesced global float4 loads)
        int jr = tid >> 2, q = tid & 3;
        float4 va = ((const float4*)(Abuf + (size_t)(j0 + jr) * LL))[q];
        float4 vb = ((const float4*)(Bbuf + (size_t)(j0 + jr) * LL))[q];
        int l4 = q * 4;
        ldsAj[(l4 + 0) * 64 + jr] = va.x; ldsAj[(l4 + 1) * 64 + jr] = va.y;
        ldsAj[(l4 + 2) * 64 + jr] = va.z; ldsAj[(l4 + 3) * 64 + jr] = va.w;
        ldsBj[(l4 + 0) * 64 + jr] = vb.x; ldsBj[(l4 + 1) * 64 + jr] = vb.y;
        ldsBj[(l4 + 2) * 64 + jr] = vb.z; ldsBj[(l4 + 3) * 64 + jr] = vb.w;
    }
    __syncthreads();

    int jo = tid & 63;   // j lane
    int ig = tid >> 6;   // i sub-group 0..3
    float aj[LL], bjr[LL], w[LL];
#pragma unroll
    for (int l = 0; l < LL; l++) {
        aj[l] = ldsAj[l * 64 + jo];
        bjr[l] = ldsBj[l * 64 + jo];
        w[l] = W_d2[l];
    }
    float bd2 = b_d2[0];
    int j = j0 + jo;

#pragma unroll 2
    for (int ii = 0; ii < 16; ii++) {
        int i = i0 + ig * 16 + ii;
        const float4* Ai4 = (const float4*)(Abuf + (size_t)i * LL);
        const float4* Bi4 = (const float4*)(Bbuf + (size_t)i * LL);
        float4 a0 = Ai4[0], a1 = Ai4[1], a2 = Ai4[2], a3 = Ai4[3];
        float4 b0 = Bi4[0], b1 = Bi4[1], b2 = Bi4[2], b3 = Bi4[3];
        float ai[LL] = {a0.x, a0.y, a0.z, a0.w, a1.x, a1.y, a1.z, a1.w,
                        a2.x, a2.y, a2.z, a2.w, a3.x, a3.y, a3.z, a3.w};
        float bi_[LL] = {b0.x, b0.y, b0.z, b0.w, b1.x, b1.y, b1.z, b1.w,
                         b2.x, b2.y, b2.z, b2.w, b3.x, b3.y, b3.z, b3.w};
        float accij = 0.f, accji = 0.f;
#pragma unroll
        for (int l = 0; l < LL; l++) {
            accij += w[l] * fmaxf(ai[l] + bjr[l], 0.f);
            accji += w[l] * fmaxf(aj[l] + bi_[l], 0.f);
        }
        float logit = 0.5f * (accij + accji) + bd2;
        float p = 1.f / (1.f + __expf(-logit));
        out[(size_t)i * NN + j] = p;
        ldsT[jo * 65 + ig * 16 + ii] = p;
    }

    if (bi != bj) {  // transposed tile write via LDS (coalesced)
        __syncthreads();
        int jj = tid >> 2, qi = tid & 3;
        float v[16];
#pragma unroll
        for (int m = 0; m < 16; m++) v[m] = ldsT[jj * 65 + qi * 16 + m];
        float4* dst = (float4*)(out + (size_t)(j0 + jj) * NN + i0 + qi * 16);
#pragma unroll
        for (int q4 = 0; q4 < 4; q4++)
            dst[q4] = make_float4(v[4 * q4], v[4 * q4 + 1], v[4 * q4 + 2], v[4 * q4 + 3]);
    }
}

extern "C" void kernel_launch(void* const* d_in, const int* in_sizes, int n_in,
                              void* d_out, int out_size, void* d_ws, size_t ws_size,
                              hipStream_t stream) {
    const float* x    = (const float*)d_in[0];
    const int*   ei   = (const int*)d_in[1];
    const float* W_in = (const float*)d_in[2];
    const float* b_in = (const float*)d_in[3];
    const float* W_msg = (const float*)d_in[4];
    const float* b_msg = (const float*)d_in[5];
    const float* W_ih = (const float*)d_in[6];
    const float* W_hh = (const float*)d_in[7];
    const float* b_ih = (const float*)d_in[8];
    const float* b_hh = (const float*)d_in[9];
    const float* W_mu = (const float*)d_in[10];
    const float* b_mu = (const float*)d_in[11];
    const float* W_ls = (const float*)d_in[12];
    const float* b_ls = (const float*)d_in[13];
    const float* W_d1 = (const float*)d_in[14];
    const float* b_d1 = (const float*)d_in[15];
    const float* W_d2 = (const float*)d_in[16];
    const float* b_d2 = (const float*)d_in[17];

    float* ws = (float*)d_ws;
    float* stateA = ws;                   // N*S
    float* stateB = stateA + NN * SS;     // N*S
    float* msg    = stateB + NN * SS;     // N*S
    float* agg0   = msg + NN * SS;        // N*S
    float* agg1   = agg0 + NN * SS;       // N*S
    float* Abuf   = agg1 + NN * SS;       // N*L
    float* Bbuf   = Abuf + NN * LL;       // N*L

    float* out_adj = (float*)d_out;
    float* out_mu  = out_adj + (size_t)NN * NN;
    float* out_ls  = out_mu + NN * LL;

    // 8 rows per 256-thread block
    enc_msg_kernel<<<NN / 8, 256, 0, stream>>>(x, W_in, b_in, W_msg, b_msg,
                                               stateA, msg, agg0);
    scatter_kernel<<<EE * SS / 256, 256, 0, stream>>>(msg, ei, agg0);

    gru_msg_kernel<<<NN / 8, 256, 0, stream>>>(
        agg0, stateA, W_ih, W_hh, b_ih, b_hh,
        W_msg + 1 * SS * SS, b_msg + 1 * SS, stateB, msg, agg1);
    scatter_kernel<<<EE * SS / 256, 256, 0, stream>>>(msg, ei, agg1);

    gru_msg_kernel<<<NN / 8, 256, 0, stream>>>(
        agg1, stateB, W_ih + SS * 3 * SS, W_hh + SS * 3 * SS, b_ih + 3 * SS, b_hh + 3 * SS,
        W_msg + 2 * SS * SS, b_msg + 2 * SS, stateA, msg, agg0);
    scatter_kernel<<<EE * SS / 256, 256, 0, stream>>>(msg, ei, agg0);

    gru_heads_kernel<<<NN / 8, 256, 0, stream>>>(
        agg0, stateA, W_ih + 2 * SS * 3 * SS, W_hh + 2 * SS * 3 * SS,
        b_ih + 2 * 3 * SS, b_hh + 2 * 3 * SS,
        W_mu, b_mu, W_ls, b_ls, W_d1, b_d1,
        out_mu, out_ls, Abuf, Bbuf);

    dec_kernel<<<528, 256, 0, stream>>>(Abuf, Bbuf, W_d2, b_d2, out_adj);
}